// Round 1
// 806.584 us; speedup vs baseline: 1.0143x; 1.0143x over previous
//
#include <hip/hip_runtime.h>

#define B_   8
#define C_   512
#define L_   256
#define HW_  4096
#define EPSV 1e-5f

typedef short  short8   __attribute__((ext_vector_type(8)));
typedef float  floatx4  __attribute__((ext_vector_type(4)));
typedef unsigned short ushort8v __attribute__((ext_vector_type(8)));

__device__ __forceinline__ unsigned short f2bf(float f) {
    unsigned u = __float_as_uint(f);
    u = (u + 0x7FFF + ((u >> 16) & 1)) >> 16;
    return (unsigned short)u;
}
__device__ __forceinline__ float bf2f(unsigned short h) {
    return __uint_as_float(((unsigned)h) << 16);
}

#define AS3 __attribute__((address_space(3)))
#define AS1 __attribute__((address_space(1)))
__device__ __forceinline__ void async_cp16(const void* g, void* l) {
    __builtin_amdgcn_global_load_lds((const AS1 void*)g, (AS3 void*)l, 16, 0, 0);
}

// staging: XOR-swizzled global source, linear LDS dest (wave-uniform base + lane*16B)
template<int STRIDE>
__device__ __forceinline__ void stage_tile(
    const unsigned short* __restrict__ Abase,
    const unsigned short* __restrict__ Bbase,
    unsigned short* smem, int bufBase, int tid, int m0, int n0, int k0)
{
#pragma unroll
    for (int it = 0; it < 2; ++it) {
        int slot = tid + it * 256;            // 0..511
        int row  = slot >> 2;                 // 0..127
        int pos  = slot & 3;
        int kg   = pos ^ ((row >> 1) & 3);    // XOR swizzle: which k-group lands here
        async_cp16(Abase + (size_t)(m0 + row) * STRIDE + k0 + kg * 8,
                   &smem[bufBase + slot * 8]);
        async_cp16(Bbase + (size_t)(n0 + row) * STRIDE + k0 + kg * 8,
                   &smem[bufBase + 4096 + slot * 8]);
    }
}

// ---------------- K0: fold BN into weights, convert to bf16 -----------------
__global__ __launch_bounds__(256) void prep_kernel(
    const float* __restrict__ Wk, const float* __restrict__ bk,
    const float* __restrict__ gk, const float* __restrict__ betak,
    const float* __restrict__ mk, const float* __restrict__ vk,
    const float* __restrict__ Wq, const float* __restrict__ bq,
    const float* __restrict__ gq, const float* __restrict__ betaq,
    const float* __restrict__ mq, const float* __restrict__ vq,
    const float* __restrict__ Wd, const float* __restrict__ bd,
    const float* __restrict__ Wu,
    unsigned short* __restrict__ Aall, float* __restrict__ biasA,
    unsigned short* __restrict__ Wub)
{
    const int NA = 4 * 768 * C_;   // 1572864
    const int NW = 4 * C_ * L_;    // 524288
    const int NB = 4 * 768;        // 3072
    int idx = blockIdx.x * 256 + threadIdx.x;
    if (idx < NA) {
        int s = idx / (768 * C_);
        int rem = idx % (768 * C_);
        int r = rem / C_, c = rem % C_;
        float w;
        if (r < 256) {
            int sl = s * L_ + r;
            float sc = gk[sl] * rsqrtf(vk[sl] + EPSV);
            w = Wk[(size_t)sl * C_ + c] * sc;
        } else if (r < 512) {
            int sl = s * L_ + (r - 256);
            float sc = gq[sl] * rsqrtf(vq[sl] + EPSV);
            w = Wq[(size_t)sl * C_ + c] * sc;
        } else {
            int sl = s * L_ + (r - 512);
            w = Wd[(size_t)sl * C_ + c];
        }
        Aall[idx] = f2bf(w);
    } else if (idx < NA + NW) {
        int i = idx - NA;
        Wub[i] = f2bf(Wu[i]);
    } else if (idx < NA + NW + NB) {
        int i = idx - NA - NW;
        int s = i / 768, r = i % 768;
        float bv;
        if (r < 256) {
            int sl = s * L_ + r;
            float sc = gk[sl] * rsqrtf(vk[sl] + EPSV);
            bv = (bk[sl] - mk[sl]) * sc + betak[sl];
        } else if (r < 512) {
            int sl = s * L_ + (r - 256);
            float sc = gq[sl] * rsqrtf(vq[sl] + EPSV);
            bv = (bq[sl] - mq[sl]) * sc + betaq[sl];
        } else {
            bv = bd[s * L_ + (r - 512)];
        }
        biasA[i] = bv;
    }
}

// ---------------- K1: transpose x [C,HW] fp32 -> xT [HW,C] bf16 -------------
__global__ __launch_bounds__(256) void transpose_kernel(
    const float* __restrict__ xf, const float* __restrict__ xg,
    const float* __restrict__ xh, const float* __restrict__ xt,
    unsigned short* __restrict__ xT)
{
    __shared__ unsigned short tile[64][66];   // [c][p], pad 66 for conflict-free
    int p0 = blockIdx.x * 64;
    int c0 = blockIdx.y * 64;
    int sb = blockIdx.z;
    int s = sb >> 3, b = sb & 7;
    const float* x = (s == 0) ? xf : (s == 1) ? xg : (s == 2) ? xh : xt;
    const float* xb = x + (size_t)b * C_ * HW_;
    int tid = threadIdx.x;
    int g = tid >> 4;          // 0..15 (16-lane group)
    int t = tid & 15;          // 0..15
    int p4 = t * 4;
#pragma unroll
    for (int i = 0; i < 4; ++i) {
        int r = g + i * 16;    // c-row 0..63
        float4 v = *(const float4*)&xb[(size_t)(c0 + r) * HW_ + p0 + p4];
        tile[r][p4 + 0] = f2bf(v.x);
        tile[r][p4 + 1] = f2bf(v.y);
        tile[r][p4 + 2] = f2bf(v.z);
        tile[r][p4 + 3] = f2bf(v.w);
    }
    __syncthreads();
    unsigned short* o = xT + (size_t)sb * HW_ * C_;
    int c4 = t * 4;
#pragma unroll
    for (int i = 0; i < 4; ++i) {
        int p = g + i * 16;    // p-row 0..63
        ushort4 u;
        u.x = tile[c4 + 0][p];
        u.y = tile[c4 + 1][p];
        u.z = tile[c4 + 2][p];
        u.w = tile[c4 + 3][p];
        *(ushort4*)&o[(size_t)(p0 + p) * C_ + c0 + c4] = u;
    }
}

// ---------------- K2: down GEMM  [768x512]x[512x4096] per (s,b) -------------
// 2-phase double-buffered: issue next-tile STAGE before current-tile compute,
// one barrier per K-step. XOR-swizzled frag reads; LDS-repacked epilogue.
__global__ __launch_bounds__(256) void down_gemm(
    const unsigned short* __restrict__ Aall, const float* __restrict__ biasA,
    const unsigned short* __restrict__ xT,
    unsigned short* __restrict__ KQV)
{
    __shared__ unsigned short smem[16384] __attribute__((aligned(16))); // 32 KB
    // buf0: A=smem[0..4095]     B=smem[4096..8191]
    // buf1: A=smem[8192..12287] B=smem[12288..16383]
    // epilogue reuses all 32 KB
    int n0 = blockIdx.x * 128;
    int m0 = blockIdx.y * 128;
    int sb = blockIdx.z;
    int s = sb >> 3;
    int tid = threadIdx.x;
    int lane = tid & 63, wave = tid >> 6;
    int wm = (wave & 1) * 64, wn = (wave >> 1) * 64;
    int quad = lane >> 4, l16 = lane & 15;
    const unsigned short* Abase = Aall + (size_t)s * 768 * C_;
    const unsigned short* Bbase = xT + (size_t)sb * HW_ * C_;

    floatx4 acc[4][4];
#pragma unroll
    for (int i = 0; i < 4; ++i)
#pragma unroll
        for (int j = 0; j < 4; ++j) acc[i][j] = (floatx4){0.f, 0.f, 0.f, 0.f};

    stage_tile<C_>(Abase, Bbase, smem, 0, tid, m0, n0, 0);
    __syncthreads();

    int cur = 0;
#pragma unroll 2
    for (int kt = 0; kt < C_ / 32; ++kt) {
        int nxt = cur ^ 8192;
        if (kt + 1 < C_ / 32)
            stage_tile<C_>(Abase, Bbase, smem, nxt, tid, m0, n0, (kt + 1) * 32);
        const unsigned short* At = &smem[cur];
        const unsigned short* Bt = &smem[cur + 4096];
        short8 a[4], bb[4];
#pragma unroll
        for (int mi = 0; mi < 4; ++mi) {
            int rr = wm + mi * 16 + l16;
            int pos = quad ^ ((rr >> 1) & 3);
            a[mi] = *(const short8*)&At[rr * 32 + pos * 8];
        }
#pragma unroll
        for (int ni = 0; ni < 4; ++ni) {
            int rr = wn + ni * 16 + l16;
            int pos = quad ^ ((rr >> 1) & 3);
            bb[ni] = *(const short8*)&Bt[rr * 32 + pos * 8];
        }
#pragma unroll
        for (int mi = 0; mi < 4; ++mi)
#pragma unroll
            for (int ni = 0; ni < 4; ++ni)
                acc[mi][ni] = __builtin_amdgcn_mfma_f32_16x16x32_bf16(
                    a[mi], bb[ni], acc[mi][ni], 0, 0, 0);
        __syncthreads();   // drains vmcnt(0): next tile staged; lgkm: reads done
        cur = nxt;
    }

    // epilogue: bias+relu, repack 128x128 bf16 tile in LDS, coalesced stores
    unsigned short* Ot = smem;   // 16384 shorts = full 32 KB
#pragma unroll
    for (int mi = 0; mi < 4; ++mi) {
        int rbase = wm + mi * 16 + quad * 4;
#pragma unroll
        for (int r = 0; r < 4; ++r) {
            int row = rbase + r;
            int gm = m0 + row;
            float bias = biasA[s * 768 + gm];
            bool doRelu = (gm < 512);
#pragma unroll
            for (int ni = 0; ni < 4; ++ni) {
                int col = wn + ni * 16 + l16;
                float v = acc[mi][ni][r] + bias;
                if (doRelu) v = fmaxf(v, 0.f);
                Ot[row * 128 + col] = f2bf(v);
            }
        }
    }
    __syncthreads();
#pragma unroll
    for (int i = 0; i < 8; ++i) {
        int fo = (tid + i * 256) * 8;   // short offset into 128x128 tile
        int row = fo >> 7;
        int col = fo & 127;
        *(ushort8v*)&KQV[((size_t)sb * 768 + m0 + row) * HW_ + n0 + col] =
            *(const ushort8v*)&Ot[fo];
    }
}

// ---------------- K3: 4x4 attention over contiguous 256-chunks --------------
__global__ __launch_bounds__(256) void attn_kernel(
    const unsigned short* __restrict__ KQV, unsigned short* __restrict__ Ctx)
{
    int gw = (blockIdx.x * 256 + threadIdx.x) >> 6;   // 0..32767
    int lane = threadIdx.x & 63;
    int b = gw >> 12;
    int j = gw & 4095;

    float qf[4][4], kf[4][4], vf[4][4];
#pragma unroll
    for (int s = 0; s < 4; ++s) {
        size_t sbase = (size_t)(s * 8 + b) * (768 * HW_) + (size_t)j * 256 + lane * 4;
        ushort4 ku = *(const ushort4*)(KQV + sbase);
        ushort4 qu = *(const ushort4*)(KQV + sbase + (size_t)256 * HW_);
        ushort4 vu = *(const ushort4*)(KQV + sbase + (size_t)512 * HW_);
        qf[s][0] = bf2f(qu.x); qf[s][1] = bf2f(qu.y); qf[s][2] = bf2f(qu.z); qf[s][3] = bf2f(qu.w);
        kf[s][0] = bf2f(ku.x); kf[s][1] = bf2f(ku.y); kf[s][2] = bf2f(ku.z); kf[s][3] = bf2f(ku.w);
        vf[s][0] = bf2f(vu.x); vf[s][1] = bf2f(vu.y); vf[s][2] = bf2f(vu.z); vf[s][3] = bf2f(vu.w);
    }
    float p[4][4];
#pragma unroll
    for (int s = 0; s < 4; ++s)
#pragma unroll
        for (int t = 0; t < 4; ++t) {
            float acc = 0.f;
#pragma unroll
            for (int e = 0; e < 4; ++e) acc += qf[s][e] * kf[t][e];
            p[s][t] = acc;
        }
#pragma unroll
    for (int off = 1; off < 64; off <<= 1)
#pragma unroll
        for (int s = 0; s < 4; ++s)
#pragma unroll
            for (int t = 0; t < 4; ++t)
                p[s][t] += __shfl_xor(p[s][t], off, 64);

    float at[4][4];
#pragma unroll
    for (int s = 0; s < 4; ++s) {
        float m = -1e30f;
#pragma unroll
        for (int t = 0; t < 4; ++t) { p[s][t] *= 0.0625f; m = fmaxf(m, p[s][t]); }
        float sm = 0.f;
#pragma unroll
        for (int t = 0; t < 4; ++t) { at[s][t] = __expf(p[s][t] - m); sm += at[s][t]; }
        float inv = 1.f / sm;
#pragma unroll
        for (int t = 0; t < 4; ++t) at[s][t] *= inv;
    }
#pragma unroll
    for (int s = 0; s < 4; ++s) {
        float c[4] = {0.f, 0.f, 0.f, 0.f};
#pragma unroll
        for (int t = 0; t < 4; ++t)
#pragma unroll
            for (int e = 0; e < 4; ++e) c[e] += at[s][t] * vf[t][e];
        ushort4 o;
        o.x = f2bf(c[0]); o.y = f2bf(c[1]); o.z = f2bf(c[2]); o.w = f2bf(c[3]);
        *(ushort4*)(Ctx + (size_t)(s * 8 + b) * (L_ * HW_) + (size_t)j * 256 + lane * 4) = o;
    }
}

// ---------------- K4: up GEMM [512x256]x[256x4096] + bias + residual --------
// 2-phase double-buffered like down_gemm
__global__ __launch_bounds__(256) void up_gemm(
    const unsigned short* __restrict__ Wub, const float* __restrict__ bu,
    const unsigned short* __restrict__ Ctx,
    const float* __restrict__ xf, const float* __restrict__ xg,
    const float* __restrict__ xh, const float* __restrict__ xt,
    float* __restrict__ out)
{
    __shared__ unsigned short smem[16384] __attribute__((aligned(16))); // 32 KB
    int n0 = blockIdx.x * 128;
    int m0 = blockIdx.y * 128;
    int sb = blockIdx.z;
    int s = sb >> 3, b = sb & 7;
    int tid = threadIdx.x;
    int lane = tid & 63, wave = tid >> 6;
    int wm = (wave & 1) * 64, wn = (wave >> 1) * 64;
    int quad = lane >> 4, l16 = lane & 15;
    const unsigned short* Abase = Wub + (size_t)s * C_ * L_;
    const unsigned short* Bbase = Ctx + (size_t)sb * HW_ * L_;

    floatx4 acc[4][4];
#pragma unroll
    for (int i = 0; i < 4; ++i)
#pragma unroll
        for (int j = 0; j < 4; ++j) acc[i][j] = (floatx4){0.f, 0.f, 0.f, 0.f};

    stage_tile<L_>(Abase, Bbase, smem, 0, tid, m0, n0, 0);
    __syncthreads();

    int cur = 0;
#pragma unroll 2
    for (int kt = 0; kt < L_ / 32; ++kt) {
        int nxt = cur ^ 8192;
        if (kt + 1 < L_ / 32)
            stage_tile<L_>(Abase, Bbase, smem, nxt, tid, m0, n0, (kt + 1) * 32);
        const unsigned short* At = &smem[cur];
        const unsigned short* Bt = &smem[cur + 4096];
        short8 a[4], bb[4];
#pragma unroll
        for (int mi = 0; mi < 4; ++mi) {
            int rr = wm + mi * 16 + l16;
            int pos = quad ^ ((rr >> 1) & 3);
            a[mi] = *(const short8*)&At[rr * 32 + pos * 8];
        }
#pragma unroll
        for (int ni = 0; ni < 4; ++ni) {
            int rr = wn + ni * 16 + l16;
            int pos = quad ^ ((rr >> 1) & 3);
            bb[ni] = *(const short8*)&Bt[rr * 32 + pos * 8];
        }
#pragma unroll
        for (int mi = 0; mi < 4; ++mi)
#pragma unroll
            for (int ni = 0; ni < 4; ++ni)
                acc[mi][ni] = __builtin_amdgcn_mfma_f32_16x16x32_bf16(
                    a[mi], bb[ni], acc[mi][ni], 0, 0, 0);
        __syncthreads();
        cur = nxt;
    }

    const float* x = (s == 0) ? xf : (s == 1) ? xg : (s == 2) ? xh : xt;
    const float* xb = x + (size_t)b * C_ * HW_;
#pragma unroll
    for (int mi = 0; mi < 4; ++mi) {
        int gmBase = m0 + wm + mi * 16 + quad * 4;
#pragma unroll
        for (int r = 0; r < 4; ++r) {
            int gm = gmBase + r;
            float bias = bu[s * C_ + gm];
#pragma unroll
            for (int ni = 0; ni < 4; ++ni) {
                int gn = n0 + wn + ni * 16 + l16;
                float rx = __builtin_nontemporal_load(&xb[(size_t)gm * HW_ + gn]);
                float v = acc[mi][ni][r] + bias + rx;
                __builtin_nontemporal_store(v, &out[((size_t)sb * C_ + gm) * HW_ + gn]);
            }
        }
    }
}

extern "C" void kernel_launch(void* const* d_in, const int* in_sizes, int n_in,
                              void* d_out, int out_size, void* d_ws, size_t ws_size,
                              hipStream_t stream) {
    (void)in_sizes; (void)n_in; (void)out_size; (void)ws_size;
    const float* xf    = (const float*)d_in[0];
    const float* xg    = (const float*)d_in[1];
    const float* xh    = (const float*)d_in[2];
    const float* xt    = (const float*)d_in[3];
    const float* Wk    = (const float*)d_in[4];
    const float* bk    = (const float*)d_in[5];
    const float* gk    = (const float*)d_in[6];
    const float* betak = (const float*)d_in[7];
    const float* mk    = (const float*)d_in[8];
    const float* vk    = (const float*)d_in[9];
    const float* Wq    = (const float*)d_in[10];
    const float* bq    = (const float*)d_in[11];
    const float* gq    = (const float*)d_in[12];
    const float* betaq = (const float*)d_in[13];
    const float* mq    = (const float*)d_in[14];
    const float* vq    = (const float*)d_in[15];
    const float* Wd    = (const float*)d_in[16];
    const float* bd    = (const float*)d_in[17];
    const float* Wu    = (const float*)d_in[18];
    const float* bu    = (const float*)d_in[19];

    char* ws = (char*)d_ws;
    unsigned short* Aall  = (unsigned short*)(ws + 0);          //   3,145,728 B
    float*          biasA = (float*)(ws + 3145728);             //      12,288 B
    unsigned short* Wub   = (unsigned short*)(ws + 3158016);    //   1,048,576 B
    unsigned short* xT    = (unsigned short*)(ws + 4206592);    // 134,217,728 B
    unsigned short* KQV   = (unsigned short*)(ws + 138424320);  // 201,326,592 B
    unsigned short* Ctx   = (unsigned short*)(ws + 339750912);  //  67,108,864 B

    prep_kernel<<<dim3(8204), 256, 0, stream>>>(
        Wk, bk, gk, betak, mk, vk, Wq, bq, gq, betaq, mq, vq, Wd, bd, Wu,
        Aall, biasA, Wub);
    transpose_kernel<<<dim3(64, 8, 32), 256, 0, stream>>>(xf, xg, xh, xt, xT);
    down_gemm<<<dim3(32, 6, 32), 256, 0, stream>>>(Aall, biasA, xT, KQV);
    attn_kernel<<<dim3(8192), 256, 0, stream>>>(KQV, Ctx);
    up_gemm<<<dim3(32, 4, 32), 256, 0, stream>>>(Wub, bu, Ctx, xf, xg, xh, xt,
                                                 (float*)d_out);
}